// Round 1
// baseline (764.119 us; speedup 1.0000x reference)
//
#include <hip/hip_runtime.h>
#include <hip/hip_bf16.h>
#include <cstdint>

#define D_MODEL 128
#define N_HEADS 8
#define HEAD_DIM 16

// ---------------------------------------------------------------------------
// QKV projection: O[n][j] = sum_k X[n][k] * W[j][k] + b[j]  for W in {Wq,Wk,Wv}
// Block: 256 threads, 32 nodes per block. X tile staged in LDS (16 KB).
// Thread owns one output column j (tid&127) and 16 nodes (half-tile).
// ---------------------------------------------------------------------------
constexpr int QKV_TN  = 32;
constexpr int QKV_NPT = 16;

__global__ __launch_bounds__(256) void qkv_kernel(
    const float* __restrict__ X,
    const float* __restrict__ Wq, const float* __restrict__ bq,
    const float* __restrict__ Wk, const float* __restrict__ bk,
    const float* __restrict__ Wv, const float* __restrict__ bv,
    float* __restrict__ Qo, float* __restrict__ Ko, float* __restrict__ Vo,
    int N)
{
  __shared__ float Xs[QKV_TN][D_MODEL];
  const int tid = threadIdx.x;
  const int n0  = blockIdx.x * QKV_TN;

  // stage X tile (32 nodes x 128 floats), float4-vectorized, coalesced
  for (int i = tid; i < QKV_TN * (D_MODEL/4); i += 256) {
    const int n = i >> 5;          // / (D_MODEL/4) == /32
    const int c = i & 31;
    float4 v = make_float4(0.f, 0.f, 0.f, 0.f);
    if (n0 + n < N)
      v = reinterpret_cast<const float4*>(X + (size_t)(n0 + n) * D_MODEL)[c];
    reinterpret_cast<float4*>(Xs[n])[c] = v;
  }
  __syncthreads();

  const int j  = tid & 127;
  const int nh = tid >> 7;   // 0 or 1 : which half of the node tile

  const float* Ws[3] = {Wq, Wk, Wv};
  const float* Bs[3] = {bq, bk, bv};
  float*       Os[3] = {Qo, Ko, Vo};

  #pragma unroll 1
  for (int m = 0; m < 3; ++m) {
    const float* __restrict__ W = Ws[m];
    const float bj = Bs[m][j];
    float acc[QKV_NPT];
    #pragma unroll
    for (int n = 0; n < QKV_NPT; ++n) acc[n] = bj;

    #pragma unroll 1
    for (int k0 = 0; k0 < D_MODEL; k0 += 8) {
      const float4 wa = reinterpret_cast<const float4*>(W + j * D_MODEL + k0)[0];
      const float4 wb = reinterpret_cast<const float4*>(W + j * D_MODEL + k0)[1];
      #pragma unroll
      for (int n = 0; n < QKV_NPT; ++n) {
        const float* xr = Xs[nh * QKV_NPT + n] + k0;
        const float4 xa = reinterpret_cast<const float4*>(xr)[0];
        const float4 xb = reinterpret_cast<const float4*>(xr)[1];
        acc[n] = fmaf(wa.x, xa.x, acc[n]);
        acc[n] = fmaf(wa.y, xa.y, acc[n]);
        acc[n] = fmaf(wa.z, xa.z, acc[n]);
        acc[n] = fmaf(wa.w, xa.w, acc[n]);
        acc[n] = fmaf(wb.x, xb.x, acc[n]);
        acc[n] = fmaf(wb.y, xb.y, acc[n]);
        acc[n] = fmaf(wb.z, xb.z, acc[n]);
        acc[n] = fmaf(wb.w, xb.w, acc[n]);
      }
    }

    float* __restrict__ O = Os[m];
    #pragma unroll
    for (int n = 0; n < QKV_NPT; ++n) {
      const int row = n0 + nh * QKV_NPT + n;
      if (row < N) O[(size_t)row * D_MODEL + j] = acc[n];
    }
  }
}

// ---------------------------------------------------------------------------
// Per-edge scores: one thread per (edge, head). 16-wide dot, exp(clip()),
// atomic segment-sum of denominators into att_sum[node][head].
// ---------------------------------------------------------------------------
__global__ __launch_bounds__(256) void score_kernel(
    const float* __restrict__ Q, const float* __restrict__ K,
    const int* __restrict__ rows, const int* __restrict__ cols,
    float* __restrict__ expatt, float* __restrict__ attsum, int E)
{
  const int t = blockIdx.x * 256 + threadIdx.x;
  if (t >= E * N_HEADS) return;
  const int e = t >> 3;
  const int h = t & 7;
  const int r = rows[e];
  const int c = cols[e];
  const float4* q = reinterpret_cast<const float4*>(Q + (size_t)r * D_MODEL + h * HEAD_DIM);
  const float4* k = reinterpret_cast<const float4*>(K + (size_t)c * D_MODEL + h * HEAD_DIM);
  float s = 0.f;
  #pragma unroll
  for (int i = 0; i < 4; ++i) {
    const float4 a = q[i];
    const float4 b = k[i];
    s += a.x * b.x + a.y * b.y + a.z * b.z + a.w * b.w;
  }
  s *= 0.25f;                       // 1/sqrt(HEAD_DIM)
  s = fminf(fmaxf(s, -10.f), 10.f);
  const float ea = __expf(s);
  expatt[t] = ea;
  atomicAdd(&attsum[r * N_HEADS + h], ea);
}

// ---------------------------------------------------------------------------
// Weighted-V scatter: one wave (64 lanes) per edge, each lane owns 2 dims.
// ---------------------------------------------------------------------------
__global__ __launch_bounds__(256) void agg_kernel(
    const float* __restrict__ V, const float* __restrict__ expatt,
    const float* __restrict__ attsum,
    const int* __restrict__ rows, const int* __restrict__ cols,
    float* __restrict__ accum, int E)
{
  const long long gt = (long long)blockIdx.x * 256 + threadIdx.x;
  const int e = (int)(gt >> 6);
  if (e >= E) return;
  const int l = threadIdx.x & 63;
  const int r = rows[e];
  const int c = cols[e];
  const int h = l >> 3;             // dims 2l,2l+1 belong to head (2l)>>4
  const float a = expatt[(size_t)e * N_HEADS + h] /
                  (attsum[r * N_HEADS + h] + 1e-8f);
  const float2 v = reinterpret_cast<const float2*>(V + (size_t)c * D_MODEL)[l];
  atomicAdd(&accum[(size_t)r * D_MODEL + 2 * l],     a * v.x);
  atomicAdd(&accum[(size_t)r * D_MODEL + 2 * l + 1], a * v.y);
}

// ---------------------------------------------------------------------------
// Residual + LayerNorm: one wave per node, lane owns 2 dims (float2).
// ---------------------------------------------------------------------------
__global__ __launch_bounds__(256) void ln_kernel(
    const float* __restrict__ accum, const float* __restrict__ X,
    const float* __restrict__ gamma, const float* __restrict__ beta,
    float* __restrict__ out, int N)
{
  const long long gt = (long long)blockIdx.x * 256 + threadIdx.x;
  const int n = (int)(gt >> 6);
  if (n >= N) return;
  const int l = threadIdx.x & 63;
  const float2 acc = reinterpret_cast<const float2*>(accum + (size_t)n * D_MODEL)[l];
  const float2 x   = reinterpret_cast<const float2*>(X     + (size_t)n * D_MODEL)[l];
  const float a0 = acc.x + x.x;
  const float a1 = acc.y + x.y;
  float s  = a0 + a1;
  float ss = a0 * a0 + a1 * a1;
  #pragma unroll
  for (int off = 32; off > 0; off >>= 1) {
    s  += __shfl_xor(s,  off, 64);
    ss += __shfl_xor(ss, off, 64);
  }
  const float mean = s * (1.f / 128.f);
  const float var  = ss * (1.f / 128.f) - mean * mean;
  const float rs   = rsqrtf(var + 1e-6f);
  const float2 g = reinterpret_cast<const float2*>(gamma)[l];
  const float2 b = reinterpret_cast<const float2*>(beta)[l];
  float2 o;
  o.x = (a0 - mean) * rs * g.x + b.x;
  o.y = (a1 - mean) * rs * g.y + b.y;
  reinterpret_cast<float2*>(out + (size_t)n * D_MODEL)[l] = o;
}

// ---------------------------------------------------------------------------
extern "C" void kernel_launch(void* const* d_in, const int* in_sizes, int n_in,
                              void* d_out, int out_size, void* d_ws, size_t ws_size,
                              hipStream_t stream)
{
  const float* X     = (const float*)d_in[0];
  const int*   ei    = (const int*)  d_in[1];
  const float* Wq    = (const float*)d_in[2];
  const float* bq    = (const float*)d_in[3];
  const float* Wk    = (const float*)d_in[4];
  const float* bk    = (const float*)d_in[5];
  const float* Wv    = (const float*)d_in[6];
  const float* bv    = (const float*)d_in[7];
  const float* gamma = (const float*)d_in[8];
  const float* beta  = (const float*)d_in[9];

  const int N = in_sizes[0] / D_MODEL;
  const int E = in_sizes[1] / 2;

  float* ws     = (float*)d_ws;
  float* Q      = ws;
  float* Kb     = Q      + (size_t)N * D_MODEL;
  float* Vb     = Kb     + (size_t)N * D_MODEL;
  float* expatt = Vb     + (size_t)N * D_MODEL;
  float* attsum = expatt + (size_t)E * N_HEADS;
  float* accum  = Q;   // alias: Q is dead after score_kernel

  hipMemsetAsync(attsum, 0, (size_t)N * N_HEADS * sizeof(float), stream);

  qkv_kernel<<<(N + QKV_TN - 1) / QKV_TN, 256, 0, stream>>>(
      X, Wq, bq, Wk, bk, Wv, bv, Q, Kb, Vb, N);

  score_kernel<<<(unsigned)(((size_t)E * N_HEADS + 255) / 256), 256, 0, stream>>>(
      Q, Kb, ei, ei + E, expatt, attsum, E);

  hipMemsetAsync(accum, 0, (size_t)N * D_MODEL * sizeof(float), stream);

  agg_kernel<<<(unsigned)(((size_t)E * 64 + 255) / 256), 256, 0, stream>>>(
      Vb, expatt, attsum, ei, ei + E, accum, E);

  ln_kernel<<<(N + 3) / 4, 256, 0, stream>>>(
      accum, X, gamma, beta, (float*)d_out, N);
}

// Round 2
// 427.721 us; speedup vs baseline: 1.7865x; 1.7865x over previous
//
#include <hip/hip_runtime.h>
#include <hip/hip_bf16.h>
#include <cstdint>

#define D_MODEL 128
#define N_HEADS 8
#define HEAD_DIM 16

// ---------------------------------------------------------------------------
// QKV projection: O[n][j] = sum_k X[n][k] * W[j][k] + b[j]  for W in {Wq,Wk,Wv}
// ---------------------------------------------------------------------------
constexpr int QKV_TN  = 32;
constexpr int QKV_NPT = 16;

__global__ __launch_bounds__(256) void qkv_kernel(
    const float* __restrict__ X,
    const float* __restrict__ Wq, const float* __restrict__ bq,
    const float* __restrict__ Wk, const float* __restrict__ bk,
    const float* __restrict__ Wv, const float* __restrict__ bv,
    float* __restrict__ Qo, float* __restrict__ Ko, float* __restrict__ Vo,
    int N)
{
  __shared__ float Xs[QKV_TN][D_MODEL];
  const int tid = threadIdx.x;
  const int n0  = blockIdx.x * QKV_TN;

  for (int i = tid; i < QKV_TN * (D_MODEL/4); i += 256) {
    const int n = i >> 5;
    const int c = i & 31;
    float4 v = make_float4(0.f, 0.f, 0.f, 0.f);
    if (n0 + n < N)
      v = reinterpret_cast<const float4*>(X + (size_t)(n0 + n) * D_MODEL)[c];
    reinterpret_cast<float4*>(Xs[n])[c] = v;
  }
  __syncthreads();

  const int j  = tid & 127;
  const int nh = tid >> 7;

  const float* Ws[3] = {Wq, Wk, Wv};
  const float* Bs[3] = {bq, bk, bv};
  float*       Os[3] = {Qo, Ko, Vo};

  #pragma unroll 1
  for (int m = 0; m < 3; ++m) {
    const float* __restrict__ W = Ws[m];
    const float bj = Bs[m][j];
    float acc[QKV_NPT];
    #pragma unroll
    for (int n = 0; n < QKV_NPT; ++n) acc[n] = bj;

    #pragma unroll 1
    for (int k0 = 0; k0 < D_MODEL; k0 += 8) {
      const float4 wa = reinterpret_cast<const float4*>(W + j * D_MODEL + k0)[0];
      const float4 wb = reinterpret_cast<const float4*>(W + j * D_MODEL + k0)[1];
      #pragma unroll
      for (int n = 0; n < QKV_NPT; ++n) {
        const float* xr = Xs[nh * QKV_NPT + n] + k0;
        const float4 xa = reinterpret_cast<const float4*>(xr)[0];
        const float4 xb = reinterpret_cast<const float4*>(xr)[1];
        acc[n] = fmaf(wa.x, xa.x, acc[n]);
        acc[n] = fmaf(wa.y, xa.y, acc[n]);
        acc[n] = fmaf(wa.z, xa.z, acc[n]);
        acc[n] = fmaf(wa.w, xa.w, acc[n]);
        acc[n] = fmaf(wb.x, xb.x, acc[n]);
        acc[n] = fmaf(wb.y, xb.y, acc[n]);
        acc[n] = fmaf(wb.z, xb.z, acc[n]);
        acc[n] = fmaf(wb.w, xb.w, acc[n]);
      }
    }

    float* __restrict__ O = Os[m];
    #pragma unroll
    for (int n = 0; n < QKV_NPT; ++n) {
      const int row = n0 + nh * QKV_NPT + n;
      if (row < N) O[(size_t)row * D_MODEL + j] = acc[n];
    }
  }
}

// ---------------------------------------------------------------------------
// CSR build: histogram -> single-block scan -> scatter
// ---------------------------------------------------------------------------
__global__ __launch_bounds__(256) void hist_kernel(
    const int* __restrict__ rows, int* __restrict__ cnt, int E)
{
  const int e = blockIdx.x * 256 + threadIdx.x;
  if (e < E) atomicAdd(&cnt[rows[e]], 1);
}

__global__ __launch_bounds__(1024) void scan_kernel(
    const int* __restrict__ cnt, int* __restrict__ row_ptr,
    int* __restrict__ row_cur, int N, int E)
{
  __shared__ int partial[1024];
  const int t = threadIdx.x;
  const int C = (N + 1023) / 1024;
  const int base = t * C;
  int sum = 0;
  for (int i = 0; i < C; ++i) {
    const int idx = base + i;
    if (idx < N) sum += cnt[idx];
  }
  partial[t] = sum;
  __syncthreads();
  for (int off = 1; off < 1024; off <<= 1) {
    int other = 0;
    if (t >= off) other = partial[t - off];
    __syncthreads();
    partial[t] += other;
    __syncthreads();
  }
  int running = partial[t] - sum;   // exclusive prefix of this chunk
  for (int i = 0; i < C; ++i) {
    const int idx = base + i;
    if (idx < N) {
      row_ptr[idx] = running;
      row_cur[idx] = running;
      running += cnt[idx];
    }
  }
  if (t == 1023) row_ptr[N] = E;
}

__global__ __launch_bounds__(256) void scatter_kernel(
    const int* __restrict__ rows, const int* __restrict__ cols,
    int* __restrict__ row_cur, int* __restrict__ csr_cols, int E)
{
  const int e = blockIdx.x * 256 + threadIdx.x;
  if (e >= E) return;
  const int pos = atomicAdd(&row_cur[rows[e]], 1);
  csr_cols[pos] = cols[e];
}

// ---------------------------------------------------------------------------
// Fused per-node attention + residual + LayerNorm.
// One wave per node; lane owns dims {2l, 2l+1}; head h = l>>3 (lanes 8h..8h+7).
// Single pass: numerator and denominator accumulate together (denominator is
// uniform over a node's edges), then divide, residual, LN.
// ---------------------------------------------------------------------------
__global__ __launch_bounds__(256) void fused_kernel(
    const float* __restrict__ Q, const float* __restrict__ K,
    const float* __restrict__ V, const float* __restrict__ X,
    const int* __restrict__ row_ptr, const int* __restrict__ csr_cols,
    const float* __restrict__ gamma, const float* __restrict__ beta,
    float* __restrict__ out, int N)
{
  const int n = blockIdx.x * 4 + (threadIdx.x >> 6);
  if (n >= N) return;
  const int l = threadIdx.x & 63;

  const float2 q = reinterpret_cast<const float2*>(Q + (size_t)n * D_MODEL)[l];
  float2 acc = make_float2(0.f, 0.f);
  float denom = 0.f;

  const int e0 = row_ptr[n];
  const int e1 = row_ptr[n + 1];
  for (int e = e0; e < e1; ++e) {
    const int c = csr_cols[e];
    const float2 k = reinterpret_cast<const float2*>(K + (size_t)c * D_MODEL)[l];
    const float2 v = reinterpret_cast<const float2*>(V + (size_t)c * D_MODEL)[l];
    float s = q.x * k.x + q.y * k.y;
    s += __shfl_xor(s, 1, 64);
    s += __shfl_xor(s, 2, 64);
    s += __shfl_xor(s, 4, 64);      // full 16-dim head dot within 8-lane group
    s *= 0.25f;                     // 1/sqrt(16)
    s = fminf(fmaxf(s, -10.f), 10.f);
    const float ea = __expf(s);
    denom += ea;
    acc.x = fmaf(ea, v.x, acc.x);
    acc.y = fmaf(ea, v.y, acc.y);
  }

  const float inv = 1.f / (denom + 1e-8f);
  const float2 x = reinterpret_cast<const float2*>(X + (size_t)n * D_MODEL)[l];
  const float a0 = acc.x * inv + x.x;
  const float a1 = acc.y * inv + x.y;

  float s  = a0 + a1;
  float ss = a0 * a0 + a1 * a1;
  #pragma unroll
  for (int off = 32; off > 0; off >>= 1) {
    s  += __shfl_xor(s,  off, 64);
    ss += __shfl_xor(ss, off, 64);
  }
  const float mean = s * (1.f / 128.f);
  const float var  = ss * (1.f / 128.f) - mean * mean;
  const float rs   = rsqrtf(var + 1e-6f);
  const float2 g = reinterpret_cast<const float2*>(gamma)[l];
  const float2 b = reinterpret_cast<const float2*>(beta)[l];
  float2 o;
  o.x = (a0 - mean) * rs * g.x + b.x;
  o.y = (a1 - mean) * rs * g.y + b.y;
  reinterpret_cast<float2*>(out + (size_t)n * D_MODEL)[l] = o;
}

// ---------------------------------------------------------------------------
extern "C" void kernel_launch(void* const* d_in, const int* in_sizes, int n_in,
                              void* d_out, int out_size, void* d_ws, size_t ws_size,
                              hipStream_t stream)
{
  const float* X     = (const float*)d_in[0];
  const int*   ei    = (const int*)  d_in[1];
  const float* Wq    = (const float*)d_in[2];
  const float* bq    = (const float*)d_in[3];
  const float* Wk    = (const float*)d_in[4];
  const float* bk    = (const float*)d_in[5];
  const float* Wv    = (const float*)d_in[6];
  const float* bv    = (const float*)d_in[7];
  const float* gamma = (const float*)d_in[8];
  const float* beta  = (const float*)d_in[9];

  const int N = in_sizes[0] / D_MODEL;
  const int E = in_sizes[1] / 2;
  const int* rows = ei;
  const int* cols = ei + E;

  float* ws       = (float*)d_ws;
  float* Q        = ws;
  float* Kb       = Q  + (size_t)N * D_MODEL;
  float* Vb       = Kb + (size_t)N * D_MODEL;
  int*   row_cnt  = (int*)(Vb + (size_t)N * D_MODEL);
  int*   row_ptr  = row_cnt + N;          // N+1 ints
  int*   row_cur  = row_ptr + N + 1;
  int*   csr_cols = row_cur + N;          // E ints

  hipMemsetAsync(row_cnt, 0, (size_t)N * sizeof(int), stream);

  hist_kernel<<<(E + 255) / 256, 256, 0, stream>>>(rows, row_cnt, E);
  scan_kernel<<<1, 1024, 0, stream>>>(row_cnt, row_ptr, row_cur, N, E);
  scatter_kernel<<<(E + 255) / 256, 256, 0, stream>>>(rows, cols, row_cur, csr_cols, E);

  qkv_kernel<<<(N + QKV_TN - 1) / QKV_TN, 256, 0, stream>>>(
      X, Wq, bq, Wk, bk, Wv, bv, Q, Kb, Vb, N);

  fused_kernel<<<(N + 3) / 4, 256, 0, stream>>>(
      Q, Kb, Vb, X, row_ptr, csr_cols, gamma, beta, (float*)d_out, N);
}

// Round 3
// 340.789 us; speedup vs baseline: 2.2422x; 1.2551x over previous
//
#include <hip/hip_runtime.h>
#include <hip/hip_bf16.h>
#include <cstdint>

#define D_MODEL 128
#define N_HEADS 8
#define HEAD_DIM 16

typedef __attribute__((ext_vector_type(8))) short bf16x8;
typedef __attribute__((ext_vector_type(4))) float f32x4;

static __device__ __forceinline__ float b2f(unsigned short u) {
  unsigned int x = ((unsigned int)u) << 16;
  return __builtin_bit_cast(float, x);
}
static __device__ __forceinline__ unsigned short f2b(float f) {
  __hip_bfloat16 h = __float2bfloat16(f);   // RNE
  return __builtin_bit_cast(unsigned short, h);
}

// ---------------------------------------------------------------------------
// fp32 -> bf16 conversion: X (nx elements) + the three 128x128 W matrices.
// Blocks [0, nxb) cover X; blocks [nxb, nxb+24) cover Wq/Wk/Wv (8 blocks each).
// ---------------------------------------------------------------------------
__global__ __launch_bounds__(256) void cvt_kernel(
    const float* __restrict__ X,
    const float* __restrict__ Wq, const float* __restrict__ Wk,
    const float* __restrict__ Wv,
    unsigned short* __restrict__ Xb, unsigned short* __restrict__ Wb,
    long long nx, int nxb)
{
  const int b = blockIdx.x;
  const float* src;
  unsigned short* dst;
  long long base;
  long long limit;
  if (b < nxb) {
    src = X; dst = Xb;
    base = ((long long)b * 256 + threadIdx.x) * 8;
    limit = nx;
  } else {
    const int wb = b - nxb;
    const int m = wb >> 3;                 // which W
    src = (m == 0) ? Wq : (m == 1) ? Wk : Wv;
    dst = Wb + (size_t)m * 16384;
    base = ((long long)(wb & 7) * 256 + threadIdx.x) * 8;
    limit = 16384;
  }
  if (base >= limit) return;
  const float4 a = reinterpret_cast<const float4*>(src + base)[0];
  const float4 c = reinterpret_cast<const float4*>(src + base)[1];
  unsigned short tmp[8];
  tmp[0] = f2b(a.x); tmp[1] = f2b(a.y); tmp[2] = f2b(a.z); tmp[3] = f2b(a.w);
  tmp[4] = f2b(c.x); tmp[5] = f2b(c.y); tmp[6] = f2b(c.z); tmp[7] = f2b(c.w);
  reinterpret_cast<uint4*>(dst + base)[0] = *reinterpret_cast<uint4*>(tmp);
}

// ---------------------------------------------------------------------------
// MFMA QKV: O[n][j] = sum_k X[n][k] * W[j][k] + b[j], bf16 in, bf16 out.
// 4 waves / block, 16 nodes per wave. 96 MFMAs (16x16x32) per wave-tile.
// A frag: lane l holds X[n0+(l&15)][ks*32 + (l>>4)*8 + j]     (16B load)
// B frag: lane l holds W[c*16+(l&15)][ks*32 + (l>>4)*8 + j]   (16B load)
// D:      lane l, reg r -> row n0+(l>>4)*4+r, col c*16+(l&15)
// ---------------------------------------------------------------------------
__global__ __launch_bounds__(256) void qkv_mfma(
    const unsigned short* __restrict__ Xb, const unsigned short* __restrict__ Wb,
    const float* __restrict__ bq, const float* __restrict__ bk,
    const float* __restrict__ bv,
    unsigned short* __restrict__ Qo, unsigned short* __restrict__ Ko,
    unsigned short* __restrict__ Vo, int N)
{
  const int wave = threadIdx.x >> 6;
  const int l    = threadIdx.x & 63;
  const int tile = blockIdx.x * 4 + wave;
  const int n0   = tile * 16;
  if (n0 >= N) return;
  const int lr = l & 15;
  const int lg = l >> 4;

  bf16x8 a[4];
  const int arow = n0 + lr;
  if (arow < N) {
    const unsigned short* xp = Xb + (size_t)arow * D_MODEL + lg * 8;
    #pragma unroll
    for (int ks = 0; ks < 4; ++ks)
      a[ks] = *reinterpret_cast<const bf16x8*>(xp + ks * 32);
  } else {
    #pragma unroll
    for (int ks = 0; ks < 4; ++ks) a[ks] = bf16x8{0,0,0,0,0,0,0,0};
  }

  const float* biases[3] = {bq, bk, bv};
  unsigned short* outs[3] = {Qo, Ko, Vo};

  #pragma unroll 1
  for (int m = 0; m < 3; ++m) {
    const unsigned short* __restrict__ W = Wb + (size_t)m * 16384;
    unsigned short* __restrict__ O = outs[m];
    const float* __restrict__ bias = biases[m];
    #pragma unroll 1
    for (int c = 0; c < 8; ++c) {
      const float bj = bias[c * 16 + lr];
      f32x4 acc = {bj, bj, bj, bj};
      const unsigned short* wp = W + (size_t)(c * 16 + lr) * D_MODEL + lg * 8;
      #pragma unroll
      for (int ks = 0; ks < 4; ++ks) {
        const bf16x8 bfr = *reinterpret_cast<const bf16x8*>(wp + ks * 32);
        acc = __builtin_amdgcn_mfma_f32_16x16x32_bf16(a[ks], bfr, acc, 0, 0, 0);
      }
      #pragma unroll
      for (int r = 0; r < 4; ++r) {
        const int orow = n0 + lg * 4 + r;
        if (orow < N) O[(size_t)orow * D_MODEL + c * 16 + lr] = f2b(acc[r]);
      }
    }
  }
}

// ---------------------------------------------------------------------------
// CSR build: histogram -> single-block scan -> scatter
// ---------------------------------------------------------------------------
__global__ __launch_bounds__(256) void hist_kernel(
    const int* __restrict__ rows, int* __restrict__ cnt, int E)
{
  const int e = blockIdx.x * 256 + threadIdx.x;
  if (e < E) atomicAdd(&cnt[rows[e]], 1);
}

__global__ __launch_bounds__(1024) void scan_kernel(
    const int* __restrict__ cnt, int* __restrict__ row_ptr,
    int* __restrict__ row_cur, int N, int E)
{
  __shared__ int partial[1024];
  const int t = threadIdx.x;
  const int C = (N + 1023) / 1024;
  const int base = t * C;
  int sum = 0;
  for (int i = 0; i < C; ++i) {
    const int idx = base + i;
    if (idx < N) sum += cnt[idx];
  }
  partial[t] = sum;
  __syncthreads();
  for (int off = 1; off < 1024; off <<= 1) {
    int other = 0;
    if (t >= off) other = partial[t - off];
    __syncthreads();
    partial[t] += other;
    __syncthreads();
  }
  int running = partial[t] - sum;
  for (int i = 0; i < C; ++i) {
    const int idx = base + i;
    if (idx < N) {
      row_ptr[idx] = running;
      row_cur[idx] = running;
      running += cnt[idx];
    }
  }
  if (t == 1023) row_ptr[N] = E;
}

__global__ __launch_bounds__(256) void scatter_kernel(
    const int* __restrict__ rows, const int* __restrict__ cols,
    int* __restrict__ row_cur, int* __restrict__ csr_cols, int E)
{
  const int e = blockIdx.x * 256 + threadIdx.x;
  if (e >= E) return;
  const int pos = atomicAdd(&row_cur[rows[e]], 1);
  csr_cols[pos] = cols[e];
}

// ---------------------------------------------------------------------------
// Fused per-node attention + residual + LayerNorm. bf16 Q/K/V, fp32 math.
// One wave per node; lane owns dims {2l, 2l+1}; head h = l>>3.
// ---------------------------------------------------------------------------
__global__ __launch_bounds__(256) void fused_kernel(
    const unsigned short* __restrict__ Q, const unsigned short* __restrict__ K,
    const unsigned short* __restrict__ V, const float* __restrict__ X,
    const int* __restrict__ row_ptr, const int* __restrict__ csr_cols,
    const float* __restrict__ gamma, const float* __restrict__ beta,
    float* __restrict__ out, int N)
{
  const int n = blockIdx.x * 4 + (threadIdx.x >> 6);
  if (n >= N) return;
  const int l = threadIdx.x & 63;

  const ushort2 qu = reinterpret_cast<const ushort2*>(Q + (size_t)n * D_MODEL)[l];
  const float qx = b2f(qu.x), qy = b2f(qu.y);
  float accx = 0.f, accy = 0.f;
  float denom = 0.f;

  const int e0 = row_ptr[n];
  const int e1 = row_ptr[n + 1];
  for (int e = e0; e < e1; ++e) {
    const int c = csr_cols[e];
    const ushort2 ku = reinterpret_cast<const ushort2*>(K + (size_t)c * D_MODEL)[l];
    const ushort2 vu = reinterpret_cast<const ushort2*>(V + (size_t)c * D_MODEL)[l];
    float s = qx * b2f(ku.x) + qy * b2f(ku.y);
    s += __shfl_xor(s, 1, 64);
    s += __shfl_xor(s, 2, 64);
    s += __shfl_xor(s, 4, 64);
    s *= 0.25f;
    s = fminf(fmaxf(s, -10.f), 10.f);
    const float ea = __expf(s);
    denom += ea;
    accx = fmaf(ea, b2f(vu.x), accx);
    accy = fmaf(ea, b2f(vu.y), accy);
  }

  const float inv = 1.f / (denom + 1e-8f);
  const float2 x = reinterpret_cast<const float2*>(X + (size_t)n * D_MODEL)[l];
  const float a0 = accx * inv + x.x;
  const float a1 = accy * inv + x.y;

  float s  = a0 + a1;
  float ss = a0 * a0 + a1 * a1;
  #pragma unroll
  for (int off = 32; off > 0; off >>= 1) {
    s  += __shfl_xor(s,  off, 64);
    ss += __shfl_xor(ss, off, 64);
  }
  const float mean = s * (1.f / 128.f);
  const float var  = ss * (1.f / 128.f) - mean * mean;
  const float rs   = rsqrtf(var + 1e-6f);
  const float2 g = reinterpret_cast<const float2*>(gamma)[l];
  const float2 b = reinterpret_cast<const float2*>(beta)[l];
  float2 o;
  o.x = (a0 - mean) * rs * g.x + b.x;
  o.y = (a1 - mean) * rs * g.y + b.y;
  reinterpret_cast<float2*>(out + (size_t)n * D_MODEL)[l] = o;
}

// ---------------------------------------------------------------------------
extern "C" void kernel_launch(void* const* d_in, const int* in_sizes, int n_in,
                              void* d_out, int out_size, void* d_ws, size_t ws_size,
                              hipStream_t stream)
{
  const float* X     = (const float*)d_in[0];
  const int*   ei    = (const int*)  d_in[1];
  const float* Wq    = (const float*)d_in[2];
  const float* bq    = (const float*)d_in[3];
  const float* Wk    = (const float*)d_in[4];
  const float* bk    = (const float*)d_in[5];
  const float* Wv    = (const float*)d_in[6];
  const float* bv    = (const float*)d_in[7];
  const float* gamma = (const float*)d_in[8];
  const float* beta  = (const float*)d_in[9];

  const int N = in_sizes[0] / D_MODEL;
  const int E = in_sizes[1] / 2;
  const int* rows = ei;
  const int* cols = ei + E;

  const size_t nd = (size_t)N * D_MODEL;
  unsigned short* Xb = (unsigned short*)d_ws;
  unsigned short* Wb = Xb + nd;
  unsigned short* Qb = Wb + 3 * 16384;
  unsigned short* Kb = Qb + nd;
  unsigned short* Vb = Kb + nd;
  int* row_cnt  = (int*)(Vb + nd);
  int* row_ptr  = row_cnt + N;
  int* row_cur  = row_ptr + N + 1;
  int* csr_cols = row_cur + N;

  hipMemsetAsync(row_cnt, 0, (size_t)N * sizeof(int), stream);

  const long long nx = (long long)nd;
  const int nxb = (int)((nx + 2047) / 2048);
  cvt_kernel<<<nxb + 24, 256, 0, stream>>>(X, Wq, Wk, Wv, Xb, Wb, nx, nxb);

  hist_kernel<<<(E + 255) / 256, 256, 0, stream>>>(rows, row_cnt, E);
  scan_kernel<<<1, 1024, 0, stream>>>(row_cnt, row_ptr, row_cur, N, E);
  scatter_kernel<<<(E + 255) / 256, 256, 0, stream>>>(rows, cols, row_cur, csr_cols, E);

  qkv_mfma<<<(N / 16 + 4) / 4, 256, 0, stream>>>(
      Xb, Wb, bq, bk, bv, Qb, Kb, Vb, N);

  fused_kernel<<<(N + 3) / 4, 256, 0, stream>>>(
      Qb, Kb, Vb, X, row_ptr, csr_cols, gamma, beta, (float*)d_out, N);
}

// Round 4
// 226.284 us; speedup vs baseline: 3.3768x; 1.5060x over previous
//
#include <hip/hip_runtime.h>
#include <hip/hip_bf16.h>
#include <cstdint>

#define D_MODEL 128
#define N_HEADS 8
#define HEAD_DIM 16

typedef __attribute__((ext_vector_type(8))) short bf16x8;
typedef __attribute__((ext_vector_type(4))) float f32x4;

static __device__ __forceinline__ float b2f(unsigned short u) {
  unsigned int x = ((unsigned int)u) << 16;
  return __builtin_bit_cast(float, x);
}
static __device__ __forceinline__ unsigned short f2b(float f) {
  __hip_bfloat16 h = __float2bfloat16(f);   // RNE
  return __builtin_bit_cast(unsigned short, h);
}

// ---------------------------------------------------------------------------
// fp32 -> bf16 conversion: X (nx elements) + the three 128x128 W matrices.
// ---------------------------------------------------------------------------
__global__ __launch_bounds__(256) void cvt_kernel(
    const float* __restrict__ X,
    const float* __restrict__ Wq, const float* __restrict__ Wk,
    const float* __restrict__ Wv,
    unsigned short* __restrict__ Xb, unsigned short* __restrict__ Wb,
    long long nx, int nxb)
{
  const int b = blockIdx.x;
  const float* src;
  unsigned short* dst;
  long long base;
  long long limit;
  if (b < nxb) {
    src = X; dst = Xb;
    base = ((long long)b * 256 + threadIdx.x) * 8;
    limit = nx;
  } else {
    const int wb = b - nxb;
    const int m = wb >> 3;                 // which W
    src = (m == 0) ? Wq : (m == 1) ? Wk : Wv;
    dst = Wb + (size_t)m * 16384;
    base = ((long long)(wb & 7) * 256 + threadIdx.x) * 8;
    limit = 16384;
  }
  if (base >= limit) return;
  const float4 a = reinterpret_cast<const float4*>(src + base)[0];
  const float4 c = reinterpret_cast<const float4*>(src + base)[1];
  unsigned short tmp[8];
  tmp[0] = f2b(a.x); tmp[1] = f2b(a.y); tmp[2] = f2b(a.z); tmp[3] = f2b(a.w);
  tmp[4] = f2b(c.x); tmp[5] = f2b(c.y); tmp[6] = f2b(c.z); tmp[7] = f2b(c.w);
  reinterpret_cast<uint4*>(dst + base)[0] = *reinterpret_cast<uint4*>(tmp);
}

// ---------------------------------------------------------------------------
// MFMA QKV: O[n][j] = sum_k X[n][k] * W[j][k] + b[j], bf16 in, bf16 out.
// ---------------------------------------------------------------------------
__global__ __launch_bounds__(256) void qkv_mfma(
    const unsigned short* __restrict__ Xb, const unsigned short* __restrict__ Wb,
    const float* __restrict__ bq, const float* __restrict__ bk,
    const float* __restrict__ bv,
    unsigned short* __restrict__ Qo, unsigned short* __restrict__ Ko,
    unsigned short* __restrict__ Vo, int N)
{
  const int wave = threadIdx.x >> 6;
  const int l    = threadIdx.x & 63;
  const int tile = blockIdx.x * 4 + wave;
  const int n0   = tile * 16;
  if (n0 >= N) return;
  const int lr = l & 15;
  const int lg = l >> 4;

  bf16x8 a[4];
  const int arow = n0 + lr;
  if (arow < N) {
    const unsigned short* xp = Xb + (size_t)arow * D_MODEL + lg * 8;
    #pragma unroll
    for (int ks = 0; ks < 4; ++ks)
      a[ks] = *reinterpret_cast<const bf16x8*>(xp + ks * 32);
  } else {
    #pragma unroll
    for (int ks = 0; ks < 4; ++ks) a[ks] = bf16x8{0,0,0,0,0,0,0,0};
  }

  const float* biases[3] = {bq, bk, bv};
  unsigned short* outs[3] = {Qo, Ko, Vo};

  #pragma unroll 1
  for (int m = 0; m < 3; ++m) {
    const unsigned short* __restrict__ W = Wb + (size_t)m * 16384;
    unsigned short* __restrict__ O = outs[m];
    const float* __restrict__ bias = biases[m];
    #pragma unroll 1
    for (int c = 0; c < 8; ++c) {
      const float bj = bias[c * 16 + lr];
      f32x4 acc = {bj, bj, bj, bj};
      const unsigned short* wp = W + (size_t)(c * 16 + lr) * D_MODEL + lg * 8;
      #pragma unroll
      for (int ks = 0; ks < 4; ++ks) {
        const bf16x8 bfr = *reinterpret_cast<const bf16x8*>(wp + ks * 32);
        acc = __builtin_amdgcn_mfma_f32_16x16x32_bf16(a[ks], bfr, acc, 0, 0, 0);
      }
      #pragma unroll
      for (int r = 0; r < 4; ++r) {
        const int orow = n0 + lg * 4 + r;
        if (orow < N) O[(size_t)orow * D_MODEL + c * 16 + lr] = f2b(acc[r]);
      }
    }
  }
}

// ---------------------------------------------------------------------------
// CSR build: histogram -> hierarchical scan -> scatter
// ---------------------------------------------------------------------------
__global__ __launch_bounds__(256) void hist_kernel(
    const int* __restrict__ rows, int* __restrict__ cnt, int E)
{
  const int e = blockIdx.x * 256 + threadIdx.x;
  if (e < E) atomicAdd(&cnt[rows[e]], 1);
}

// per-block (1024-element chunk) sums
__global__ __launch_bounds__(256) void partial_kernel(
    const int* __restrict__ cnt, int* __restrict__ bsum, int N)
{
  __shared__ int wsum[4];
  const int t = threadIdx.x;
  const int base = blockIdx.x * 1024 + t * 4;
  int s = 0;
  #pragma unroll
  for (int i = 0; i < 4; ++i)
    if (base + i < N) s += cnt[base + i];
  #pragma unroll
  for (int off = 32; off > 0; off >>= 1) s += __shfl_xor(s, off, 64);
  if ((t & 63) == 0) wsum[t >> 6] = s;
  __syncthreads();
  if (t == 0) bsum[blockIdx.x] = wsum[0] + wsum[1] + wsum[2] + wsum[3];
}

// exclusive scan of block sums (handles any nb via 256-wide passes + carry)
__global__ __launch_bounds__(256) void scansums_kernel(
    const int* __restrict__ bsum, int* __restrict__ boff, int nb)
{
  __shared__ int p[256];
  __shared__ int carry_s;
  const int t = threadIdx.x;
  if (t == 0) carry_s = 0;
  __syncthreads();
  for (int c0 = 0; c0 < nb; c0 += 256) {
    const int v = (c0 + t < nb) ? bsum[c0 + t] : 0;
    p[t] = v;
    __syncthreads();
    for (int off = 1; off < 256; off <<= 1) {
      const int other = (t >= off) ? p[t - off] : 0;
      __syncthreads();
      p[t] += other;
      __syncthreads();
    }
    const int carry = carry_s;
    if (c0 + t < nb) boff[c0 + t] = carry + p[t] - v;
    __syncthreads();
    if (t == 0) carry_s = carry + p[255];
    __syncthreads();
  }
}

// per-chunk exclusive scan + block offset -> row_ptr / row_cur
__global__ __launch_bounds__(256) void emit_kernel(
    const int* __restrict__ cnt, const int* __restrict__ boff,
    int* __restrict__ row_ptr, int* __restrict__ row_cur, int N, int E)
{
  __shared__ int psum[256];
  const int t = threadIdx.x;
  const int base = blockIdx.x * 1024 + t * 4;
  int v[4];
  #pragma unroll
  for (int i = 0; i < 4; ++i)
    v[i] = (base + i < N) ? cnt[base + i] : 0;
  const int local = v[0] + v[1] + v[2] + v[3];
  psum[t] = local;
  __syncthreads();
  for (int off = 1; off < 256; off <<= 1) {
    const int other = (t >= off) ? psum[t - off] : 0;
    __syncthreads();
    psum[t] += other;
    __syncthreads();
  }
  int pre = boff[blockIdx.x] + psum[t] - local;
  #pragma unroll
  for (int i = 0; i < 4; ++i) {
    const int idx = base + i;
    if (idx < N) {
      row_ptr[idx] = pre;
      row_cur[idx] = pre;
      pre += v[i];
    }
  }
  if (blockIdx.x == 0 && t == 0) row_ptr[N] = E;
}

__global__ __launch_bounds__(256) void scatter_kernel(
    const int* __restrict__ rows, const int* __restrict__ cols,
    int* __restrict__ row_cur, int* __restrict__ csr_cols, int E)
{
  const int e = blockIdx.x * 256 + threadIdx.x;
  if (e >= E) return;
  const int pos = atomicAdd(&row_cur[rows[e]], 1);
  csr_cols[pos] = cols[e];
}

// ---------------------------------------------------------------------------
// Fused per-node attention + residual + LayerNorm. bf16 Q/K/V, fp32 math.
// ---------------------------------------------------------------------------
__global__ __launch_bounds__(256) void fused_kernel(
    const unsigned short* __restrict__ Q, const unsigned short* __restrict__ K,
    const unsigned short* __restrict__ V, const float* __restrict__ X,
    const int* __restrict__ row_ptr, const int* __restrict__ csr_cols,
    const float* __restrict__ gamma, const float* __restrict__ beta,
    float* __restrict__ out, int N)
{
  const int n = blockIdx.x * 4 + (threadIdx.x >> 6);
  if (n >= N) return;
  const int l = threadIdx.x & 63;

  const ushort2 qu = reinterpret_cast<const ushort2*>(Q + (size_t)n * D_MODEL)[l];
  const float qx = b2f(qu.x), qy = b2f(qu.y);
  float accx = 0.f, accy = 0.f;
  float denom = 0.f;

  const int e0 = row_ptr[n];
  const int e1 = row_ptr[n + 1];
  for (int e = e0; e < e1; ++e) {
    const int c = csr_cols[e];
    const ushort2 ku = reinterpret_cast<const ushort2*>(K + (size_t)c * D_MODEL)[l];
    const ushort2 vu = reinterpret_cast<const ushort2*>(V + (size_t)c * D_MODEL)[l];
    float s = qx * b2f(ku.x) + qy * b2f(ku.y);
    s += __shfl_xor(s, 1, 64);
    s += __shfl_xor(s, 2, 64);
    s += __shfl_xor(s, 4, 64);
    s *= 0.25f;
    s = fminf(fmaxf(s, -10.f), 10.f);
    const float ea = __expf(s);
    denom += ea;
    accx = fmaf(ea, b2f(vu.x), accx);
    accy = fmaf(ea, b2f(vu.y), accy);
  }

  const float inv = 1.f / (denom + 1e-8f);
  const float2 x = reinterpret_cast<const float2*>(X + (size_t)n * D_MODEL)[l];
  const float a0 = accx * inv + x.x;
  const float a1 = accy * inv + x.y;

  float s  = a0 + a1;
  float ss = a0 * a0 + a1 * a1;
  #pragma unroll
  for (int off = 32; off > 0; off >>= 1) {
    s  += __shfl_xor(s,  off, 64);
    ss += __shfl_xor(ss, off, 64);
  }
  const float mean = s * (1.f / 128.f);
  const float var  = ss * (1.f / 128.f) - mean * mean;
  const float rs   = rsqrtf(var + 1e-6f);
  const float2 g = reinterpret_cast<const float2*>(gamma)[l];
  const float2 b = reinterpret_cast<const float2*>(beta)[l];
  float2 o;
  o.x = (a0 - mean) * rs * g.x + b.x;
  o.y = (a1 - mean) * rs * g.y + b.y;
  reinterpret_cast<float2*>(out + (size_t)n * D_MODEL)[l] = o;
}

// ---------------------------------------------------------------------------
extern "C" void kernel_launch(void* const* d_in, const int* in_sizes, int n_in,
                              void* d_out, int out_size, void* d_ws, size_t ws_size,
                              hipStream_t stream)
{
  const float* X     = (const float*)d_in[0];
  const int*   ei    = (const int*)  d_in[1];
  const float* Wq    = (const float*)d_in[2];
  const float* bq    = (const float*)d_in[3];
  const float* Wk    = (const float*)d_in[4];
  const float* bk    = (const float*)d_in[5];
  const float* Wv    = (const float*)d_in[6];
  const float* bv    = (const float*)d_in[7];
  const float* gamma = (const float*)d_in[8];
  const float* beta  = (const float*)d_in[9];

  const int N = in_sizes[0] / D_MODEL;
  const int E = in_sizes[1] / 2;
  const int* rows = ei;
  const int* cols = ei + E;

  const size_t nd = (size_t)N * D_MODEL;
  unsigned short* Xb = (unsigned short*)d_ws;
  unsigned short* Wb = Xb + nd;
  unsigned short* Qb = Wb + 3 * 16384;
  unsigned short* Kb = Qb + nd;
  unsigned short* Vb = Kb + nd;
  int* row_cnt  = (int*)(Vb + nd);
  int* row_ptr  = row_cnt + N;
  int* row_cur  = row_ptr + N + 1;
  int* csr_cols = row_cur + N;
  int* bsum     = csr_cols + E;
  int* boff     = bsum + ((N + 1023) / 1024) + 1;

  const int nb = (N + 1023) / 1024;

  hipMemsetAsync(row_cnt, 0, (size_t)N * sizeof(int), stream);

  const long long nx = (long long)nd;
  const int nxb = (int)((nx + 2047) / 2048);
  cvt_kernel<<<nxb + 24, 256, 0, stream>>>(X, Wq, Wk, Wv, Xb, Wb, nx, nxb);

  hist_kernel<<<(E + 255) / 256, 256, 0, stream>>>(rows, row_cnt, E);
  partial_kernel<<<nb, 256, 0, stream>>>(row_cnt, bsum, N);
  scansums_kernel<<<1, 256, 0, stream>>>(bsum, boff, nb);
  emit_kernel<<<nb, 256, 0, stream>>>(row_cnt, boff, row_ptr, row_cur, N, E);
  scatter_kernel<<<(E + 255) / 256, 256, 0, stream>>>(rows, cols, row_cur, csr_cols, E);

  qkv_mfma<<<(N / 16 + 4) / 4, 256, 0, stream>>>(
      Xb, Wb, bq, bk, bv, Qb, Kb, Vb, N);

  fused_kernel<<<(N + 3) / 4, 256, 0, stream>>>(
      Qb, Kb, Vb, X, row_ptr, csr_cols, gamma, beta, (float*)d_out, N);
}

// Round 5
// 204.158 us; speedup vs baseline: 3.7428x; 1.1084x over previous
//
#include <hip/hip_runtime.h>
#include <hip/hip_bf16.h>
#include <cstdint>

#define D_MODEL 128
#define N_HEADS 8
#define HEAD_DIM 16

typedef __attribute__((ext_vector_type(8))) short bf16x8;
typedef __attribute__((ext_vector_type(4))) float f32x4;

static __device__ __forceinline__ float b2f(unsigned short u) {
  unsigned int x = ((unsigned int)u) << 16;
  return __builtin_bit_cast(float, x);
}
static __device__ __forceinline__ unsigned short f2b(float f) {
  __hip_bfloat16 h = __float2bfloat16(f);   // RNE
  return __builtin_bit_cast(unsigned short, h);
}

// ---------------------------------------------------------------------------
// fp32 -> bf16 conversion: X (nx elements) + the three 128x128 W matrices.
// ---------------------------------------------------------------------------
__global__ __launch_bounds__(256) void cvt_kernel(
    const float* __restrict__ X,
    const float* __restrict__ Wq, const float* __restrict__ Wk,
    const float* __restrict__ Wv,
    unsigned short* __restrict__ Xb, unsigned short* __restrict__ Wb,
    long long nx, int nxb)
{
  const int b = blockIdx.x;
  const float* src;
  unsigned short* dst;
  long long base;
  long long limit;
  if (b < nxb) {
    src = X; dst = Xb;
    base = ((long long)b * 256 + threadIdx.x) * 8;
    limit = nx;
  } else {
    const int wb = b - nxb;
    const int m = wb >> 3;                 // which W
    src = (m == 0) ? Wq : (m == 1) ? Wk : Wv;
    dst = Wb + (size_t)m * 16384;
    base = ((long long)(wb & 7) * 256 + threadIdx.x) * 8;
    limit = 16384;
  }
  if (base >= limit) return;
  const float4 a = reinterpret_cast<const float4*>(src + base)[0];
  const float4 c = reinterpret_cast<const float4*>(src + base)[1];
  unsigned short tmp[8];
  tmp[0] = f2b(a.x); tmp[1] = f2b(a.y); tmp[2] = f2b(a.z); tmp[3] = f2b(a.w);
  tmp[4] = f2b(c.x); tmp[5] = f2b(c.y); tmp[6] = f2b(c.z); tmp[7] = f2b(c.w);
  reinterpret_cast<uint4*>(dst + base)[0] = *reinterpret_cast<uint4*>(tmp);
}

// ---------------------------------------------------------------------------
// MFMA QKV: O[n][j] = sum_k X[n][k] * W[j][k] + b[j], bf16 in, bf16 out.
// ---------------------------------------------------------------------------
__global__ __launch_bounds__(256) void qkv_mfma(
    const unsigned short* __restrict__ Xb, const unsigned short* __restrict__ Wb,
    const float* __restrict__ bq, const float* __restrict__ bk,
    const float* __restrict__ bv,
    unsigned short* __restrict__ Qo, unsigned short* __restrict__ Ko,
    unsigned short* __restrict__ Vo, int N)
{
  const int wave = threadIdx.x >> 6;
  const int l    = threadIdx.x & 63;
  const int tile = blockIdx.x * 4 + wave;
  const int n0   = tile * 16;
  if (n0 >= N) return;
  const int lr = l & 15;
  const int lg = l >> 4;

  bf16x8 a[4];
  const int arow = n0 + lr;
  if (arow < N) {
    const unsigned short* xp = Xb + (size_t)arow * D_MODEL + lg * 8;
    #pragma unroll
    for (int ks = 0; ks < 4; ++ks)
      a[ks] = *reinterpret_cast<const bf16x8*>(xp + ks * 32);
  } else {
    #pragma unroll
    for (int ks = 0; ks < 4; ++ks) a[ks] = bf16x8{0,0,0,0,0,0,0,0};
  }

  const float* biases[3] = {bq, bk, bv};
  unsigned short* outs[3] = {Qo, Ko, Vo};

  #pragma unroll 1
  for (int m = 0; m < 3; ++m) {
    const unsigned short* __restrict__ W = Wb + (size_t)m * 16384;
    unsigned short* __restrict__ O = outs[m];
    const float* __restrict__ bias = biases[m];
    #pragma unroll 1
    for (int c = 0; c < 8; ++c) {
      const float bj = bias[c * 16 + lr];
      f32x4 acc = {bj, bj, bj, bj};
      const unsigned short* wp = W + (size_t)(c * 16 + lr) * D_MODEL + lg * 8;
      #pragma unroll
      for (int ks = 0; ks < 4; ++ks) {
        const bf16x8 bfr = *reinterpret_cast<const bf16x8*>(wp + ks * 32);
        acc = __builtin_amdgcn_mfma_f32_16x16x32_bf16(a[ks], bfr, acc, 0, 0, 0);
      }
      #pragma unroll
      for (int r = 0; r < 4; ++r) {
        const int orow = n0 + lg * 4 + r;
        if (orow < N) O[(size_t)orow * D_MODEL + c * 16 + lr] = f2b(acc[r]);
      }
    }
  }
}

// ---------------------------------------------------------------------------
// CSR build: histogram -> hierarchical scan -> scatter
// ---------------------------------------------------------------------------
__global__ __launch_bounds__(256) void hist_kernel(
    const int* __restrict__ rows, int* __restrict__ cnt, int E)
{
  const int e = blockIdx.x * 256 + threadIdx.x;
  if (e < E) atomicAdd(&cnt[rows[e]], 1);
}

__global__ __launch_bounds__(256) void partial_kernel(
    const int* __restrict__ cnt, int* __restrict__ bsum, int N)
{
  __shared__ int wsum[4];
  const int t = threadIdx.x;
  const int base = blockIdx.x * 1024 + t * 4;
  int s = 0;
  #pragma unroll
  for (int i = 0; i < 4; ++i)
    if (base + i < N) s += cnt[base + i];
  #pragma unroll
  for (int off = 32; off > 0; off >>= 1) s += __shfl_xor(s, off, 64);
  if ((t & 63) == 0) wsum[t >> 6] = s;
  __syncthreads();
  if (t == 0) bsum[blockIdx.x] = wsum[0] + wsum[1] + wsum[2] + wsum[3];
}

__global__ __launch_bounds__(256) void scansums_kernel(
    const int* __restrict__ bsum, int* __restrict__ boff, int nb)
{
  __shared__ int p[256];
  __shared__ int carry_s;
  const int t = threadIdx.x;
  if (t == 0) carry_s = 0;
  __syncthreads();
  for (int c0 = 0; c0 < nb; c0 += 256) {
    const int v = (c0 + t < nb) ? bsum[c0 + t] : 0;
    p[t] = v;
    __syncthreads();
    for (int off = 1; off < 256; off <<= 1) {
      const int other = (t >= off) ? p[t - off] : 0;
      __syncthreads();
      p[t] += other;
      __syncthreads();
    }
    const int carry = carry_s;
    if (c0 + t < nb) boff[c0 + t] = carry + p[t] - v;
    __syncthreads();
    if (t == 0) carry_s = carry + p[255];
    __syncthreads();
  }
}

__global__ __launch_bounds__(256) void emit_kernel(
    const int* __restrict__ cnt, const int* __restrict__ boff,
    int* __restrict__ row_ptr, int* __restrict__ row_cur, int N, int E)
{
  __shared__ int psum[256];
  const int t = threadIdx.x;
  const int base = blockIdx.x * 1024 + t * 4;
  int v[4];
  #pragma unroll
  for (int i = 0; i < 4; ++i)
    v[i] = (base + i < N) ? cnt[base + i] : 0;
  const int local = v[0] + v[1] + v[2] + v[3];
  psum[t] = local;
  __syncthreads();
  for (int off = 1; off < 256; off <<= 1) {
    const int other = (t >= off) ? psum[t - off] : 0;
    __syncthreads();
    psum[t] += other;
    __syncthreads();
  }
  int pre = boff[blockIdx.x] + psum[t] - local;
  #pragma unroll
  for (int i = 0; i < 4; ++i) {
    const int idx = base + i;
    if (idx < N) {
      row_ptr[idx] = pre;
      row_cur[idx] = pre;
      pre += v[i];
    }
  }
  if (blockIdx.x == 0 && t == 0) row_ptr[N] = E;
}

__global__ __launch_bounds__(256) void scatter_kernel(
    const int* __restrict__ rows, const int* __restrict__ cols,
    int* __restrict__ row_cur, int* __restrict__ csr_cols, int E)
{
  const int e = blockIdx.x * 256 + threadIdx.x;
  if (e >= E) return;
  const int pos = atomicAdd(&row_cur[rows[e]], 1);
  csr_cols[pos] = cols[e];
}

// ---------------------------------------------------------------------------
// Fused per-node attention + residual + LayerNorm. bf16 Q/K/V, fp32 math.
// One wave per node. Edges processed 8 per chunk:
//  Phase 1: lane = (g = l>>3 edge slot, h = l&7 head). Lane loads K[c_g]
//           head-h 16 dims (2x16B; 8 h-lanes cover the full 256B row) and
//           computes the 16-wide dot in-lane. exp once per (edge,head).
//  Phase 2: lane owns output dims {2l,2l+1} (head hd=l>>3); per edge slot j,
//           shfl (c, ea) from lane j*8+hd, gather V, accumulate numerator.
// Denominator reduced once per node at the end (lanes same-h: xor 8,16,32).
// ---------------------------------------------------------------------------
__global__ __launch_bounds__(256) void fused_kernel(
    const unsigned short* __restrict__ Q, const unsigned short* __restrict__ K,
    const unsigned short* __restrict__ V, const float* __restrict__ X,
    const int* __restrict__ row_ptr, const int* __restrict__ csr_cols,
    const float* __restrict__ gamma, const float* __restrict__ beta,
    float* __restrict__ out, int N)
{
  const int n = blockIdx.x * 4 + (threadIdx.x >> 6);
  if (n >= N) return;
  const int l  = threadIdx.x & 63;
  const int h  = l & 7;    // phase-1 head
  const int g  = l >> 3;   // phase-1 edge slot
  const int hd = l >> 3;   // phase-2 head owning dims {2l, 2l+1}

  // Q head-h dims as fp32 (broadcast across the 8 g-lanes sharing h)
  float qf[16];
  {
    const unsigned short* qp = Q + (size_t)n * D_MODEL + h * HEAD_DIM;
    const bf16x8 q0 = *reinterpret_cast<const bf16x8*>(qp);
    const bf16x8 q1 = *reinterpret_cast<const bf16x8*>(qp + 8);
    #pragma unroll
    for (int i = 0; i < 8; ++i) {
      qf[i]     = b2f((unsigned short)q0[i]);
      qf[8 + i] = b2f((unsigned short)q1[i]);
    }
  }

  float accx = 0.f, accy = 0.f, dlane = 0.f;
  const int e0 = row_ptr[n];
  const int e1 = row_ptr[n + 1];

  for (int eb = e0; eb < e1; eb += 8) {
    // ---- phase 1: scores for 8 edges ----
    const int  eg    = eb + g;
    const bool valid = eg < e1;
    const int  c     = valid ? csr_cols[eg] : 0;

    const unsigned short* kp = K + (size_t)c * D_MODEL + h * HEAD_DIM;
    const bf16x8 k0 = *reinterpret_cast<const bf16x8*>(kp);
    const bf16x8 k1 = *reinterpret_cast<const bf16x8*>(kp + 8);
    float s = 0.f;
    #pragma unroll
    for (int i = 0; i < 8; ++i) {
      s = fmaf(qf[i],     b2f((unsigned short)k0[i]), s);
      s = fmaf(qf[8 + i], b2f((unsigned short)k1[i]), s);
    }
    s *= 0.25f;                         // 1/sqrt(16)
    s = fminf(fmaxf(s, -10.f), 10.f);
    const float ea = valid ? __expf(s) : 0.f;
    dlane += ea;

    // ---- phase 2: gather V, accumulate numerator ----
    const int nj = min(8, e1 - eb);     // wave-uniform
    #pragma unroll
    for (int j = 0; j < 8; ++j) {
      if (j >= nj) break;
      const int   src = j * 8 + hd;
      const float aj  = __shfl(ea, src, 64);
      const int   cj  = __shfl(c,  src, 64);
      const ushort2 vu = reinterpret_cast<const ushort2*>(V + (size_t)cj * D_MODEL)[l];
      accx = fmaf(aj, b2f(vu.x), accx);
      accy = fmaf(aj, b2f(vu.y), accy);
    }
  }

  // denominator: sum over the 8 g-lanes sharing head h (bits 3,4,5)
  dlane += __shfl_xor(dlane, 8,  64);
  dlane += __shfl_xor(dlane, 16, 64);
  dlane += __shfl_xor(dlane, 32, 64);
  const float denom = __shfl(dlane, hd, 64);   // lane hd holds head h=hd

  const float inv = 1.f / (denom + 1e-8f);
  const float2 x = reinterpret_cast<const float2*>(X + (size_t)n * D_MODEL)[l];
  const float a0 = accx * inv + x.x;
  const float a1 = accy * inv + x.y;

  float sm  = a0 + a1;
  float ss = a0 * a0 + a1 * a1;
  #pragma unroll
  for (int off = 32; off > 0; off >>= 1) {
    sm += __shfl_xor(sm, off, 64);
    ss += __shfl_xor(ss, off, 64);
  }
  const float mean = sm * (1.f / 128.f);
  const float var  = ss * (1.f / 128.f) - mean * mean;
  const float rs   = rsqrtf(var + 1e-6f);
  const float2 gm = reinterpret_cast<const float2*>(gamma)[l];
  const float2 bt = reinterpret_cast<const float2*>(beta)[l];
  float2 o;
  o.x = (a0 - mean) * rs * gm.x + bt.x;
  o.y = (a1 - mean) * rs * gm.y + bt.y;
  reinterpret_cast<float2*>(out + (size_t)n * D_MODEL)[l] = o;
}

// ---------------------------------------------------------------------------
extern "C" void kernel_launch(void* const* d_in, const int* in_sizes, int n_in,
                              void* d_out, int out_size, void* d_ws, size_t ws_size,
                              hipStream_t stream)
{
  const float* X     = (const float*)d_in[0];
  const int*   ei    = (const int*)  d_in[1];
  const float* Wq    = (const float*)d_in[2];
  const float* bq    = (const float*)d_in[3];
  const float* Wk    = (const float*)d_in[4];
  const float* bk    = (const float*)d_in[5];
  const float* Wv    = (const float*)d_in[6];
  const float* bv    = (const float*)d_in[7];
  const float* gamma = (const float*)d_in[8];
  const float* beta  = (const float*)d_in[9];

  const int N = in_sizes[0] / D_MODEL;
  const int E = in_sizes[1] / 2;
  const int* rows = ei;
  const int* cols = ei + E;

  const size_t nd = (size_t)N * D_MODEL;
  unsigned short* Xb = (unsigned short*)d_ws;
  unsigned short* Wb = Xb + nd;
  unsigned short* Qb = Wb + 3 * 16384;
  unsigned short* Kb = Qb + nd;
  unsigned short* Vb = Kb + nd;
  int* row_cnt  = (int*)(Vb + nd);
  int* row_ptr  = row_cnt + N;
  int* row_cur  = row_ptr + N + 1;
  int* csr_cols = row_cur + N;
  int* bsum     = csr_cols + E;
  int* boff     = bsum + ((N + 1023) / 1024) + 1;

  const int nb = (N + 1023) / 1024;

  hipMemsetAsync(row_cnt, 0, (size_t)N * sizeof(int), stream);

  const long long nx = (long long)nd;
  const int nxb = (int)((nx + 2047) / 2048);
  cvt_kernel<<<nxb + 24, 256, 0, stream>>>(X, Wq, Wk, Wv, Xb, Wb, nx, nxb);

  hist_kernel<<<(E + 255) / 256, 256, 0, stream>>>(rows, row_cnt, E);
  partial_kernel<<<nb, 256, 0, stream>>>(row_cnt, bsum, N);
  scansums_kernel<<<1, 256, 0, stream>>>(bsum, boff, nb);
  emit_kernel<<<nb, 256, 0, stream>>>(row_cnt, boff, row_ptr, row_cur, N, E);
  scatter_kernel<<<(E + 255) / 256, 256, 0, stream>>>(rows, cols, row_cur, csr_cols, E);

  qkv_mfma<<<(N / 16 + 4) / 4, 256, 0, stream>>>(
      Xb, Wb, bq, bk, bv, Qb, Kb, Vb, N);

  fused_kernel<<<(N + 3) / 4, 256, 0, stream>>>(
      Qb, Kb, Vb, X, row_ptr, csr_cols, gamma, beta, (float*)d_out, N);
}